// Round 1
// baseline (604.091 us; speedup 1.0000x reference)
//
#include <hip/hip_runtime.h>
#include <math.h>

#define BSZ   8
#define NSEQ  1024
#define DIM   512
#define NH    8
#define DH    64
#define INNER 512
#define NTOK  (BSZ*NSEQ)     // 8192
#define QKVN  (3*INNER)      // 1536

// ---------------------------------------------------------------------------
// Kernel 1: qkv = x @ w_qkv + b_qkv, fused SE(3) pose transform, scatter to
// q/k/v buffers in [B,H,N,DH] layout.
// Tile 64(tokens) x 64(features), 256 threads, 4x4 micro-tile per thread.
// Micro-tile columns are 4-aligned => each thread's 4 columns = one SE(3)
// group of one head. Pose applied in epilogue.
// ---------------------------------------------------------------------------
__global__ __launch_bounds__(256) void qkv_pose_kernel(
    const float* __restrict__ x, const float* __restrict__ w,
    const float* __restrict__ bias, const float* __restrict__ rot,
    const float* __restrict__ trans,
    float* __restrict__ qb, float* __restrict__ kb, float* __restrict__ vb)
{
    __shared__ __align__(16) float As[16][68];  // As[k][row]  (A transposed)
    __shared__ __align__(16) float Bs[16][68];  // Bs[k][col]

    const int tid = threadIdx.x;
    const int tx = tid & 15, ty = tid >> 4;
    const int bx = blockIdx.x;   // feature tile (24)
    const int by = blockIdx.y;   // token tile (128)

    float acc[4][4] = {};

    const int arow = tid >> 2;            // 0..63
    const int akq  = (tid & 3) * 4;       // 0,4,8,12
    const int brow = tid >> 4;            // 0..15
    const int bc4  = (tid & 15) * 4;      // 0..60

    const float* xA = x + (size_t)(by*64 + arow)*DIM + akq;
    const float* wB = w + (size_t)brow*QKVN + bx*64 + bc4;

    for (int k0 = 0; k0 < DIM; k0 += 16) {
        float4 av = *(const float4*)(xA + k0);
        As[akq+0][arow] = av.x; As[akq+1][arow] = av.y;
        As[akq+2][arow] = av.z; As[akq+3][arow] = av.w;
        *(float4*)&Bs[brow][bc4] = *(const float4*)(wB + (size_t)k0*QKVN);
        __syncthreads();
#pragma unroll
        for (int kk = 0; kk < 16; kk++) {
            float a[4], b[4];
            *(float4*)a = *(const float4*)&As[kk][ty*4];
            *(float4*)b = *(const float4*)&Bs[kk][tx*4];
#pragma unroll
            for (int i = 0; i < 4; i++)
#pragma unroll
                for (int j = 0; j < 4; j++)
                    acc[i][j] += a[i]*b[j];
        }
        __syncthreads();
    }

    // epilogue: bias + SE(3) pose, scatter to [B,H,N,DH]
    const int c0  = bx*64 + tx*4;
    const int sec = c0 >> 9;        // 0=q 1=k 2=v
    const int f   = c0 & 511;
    const int h   = f >> 6;
    const int d   = f & 63;
    const float bv0 = bias[c0+0], bv1 = bias[c0+1], bv2 = bias[c0+2], bv3 = bias[c0+3];

#pragma unroll
    for (int i = 0; i < 4; i++) {
        const int r  = by*64 + ty*4 + i;       // global token
        const int bb = r >> 10;
        const int n  = r & 1023;
        const float* R = rot   + (size_t)(bb*NSEQ + n)*9;
        const float* T = trans + (size_t)(bb*NSEQ + n)*3;
        const float g0 = acc[i][0]+bv0, g1 = acc[i][1]+bv1;
        const float g2 = acc[i][2]+bv2, g3 = acc[i][3]+bv3;
        float o0, o1, o2, o3;
        if (sec == 0) {
            // q' = P_qinv^T g : o[ii<3] = R[ii,:]·g ; o3 = t_inv·g[0:3] + g3
            o0 = R[0]*g0 + R[1]*g1 + R[2]*g2;
            o1 = R[3]*g0 + R[4]*g1 + R[5]*g2;
            o2 = R[6]*g0 + R[7]*g1 + R[8]*g2;
            const float ti0 = -(R[0]*T[0] + R[3]*T[1] + R[6]*T[2]);
            const float ti1 = -(R[1]*T[0] + R[4]*T[1] + R[7]*T[2]);
            const float ti2 = -(R[2]*T[0] + R[5]*T[1] + R[8]*T[2]);
            o3 = ti0*g0 + ti1*g1 + ti2*g2 + g3;
        } else {
            // k'/v' = P_kv g : o[ii<3] = R[ii,:]·g + t[ii]*g3 ; o3 = g3
            o0 = R[0]*g0 + R[1]*g1 + R[2]*g2 + T[0]*g3;
            o1 = R[3]*g0 + R[4]*g1 + R[5]*g2 + T[1]*g3;
            o2 = R[6]*g0 + R[7]*g1 + R[8]*g2 + T[2]*g3;
            o3 = g3;
        }
        float* dst = (sec == 0 ? qb : (sec == 1 ? kb : vb))
                     + ((size_t)((bb*NH + h)*NSEQ + n))*DH + d;
        float4 ov = {o0, o1, o2, o3};
        *(float4*)dst = ov;
    }
}

// ---------------------------------------------------------------------------
// Kernel 2: flash attention per (b,h, 64-row Q tile) + inverse pose + merge.
// 256 threads; 4x4 micro-tiles for S and O.
// ---------------------------------------------------------------------------
__global__ __launch_bounds__(256) void attn_kernel(
    const float* __restrict__ qb, const float* __restrict__ kb,
    const float* __restrict__ vb, const float* __restrict__ rot,
    const float* __restrict__ trans, float* __restrict__ om)
{
    __shared__ __align__(16) float Qt[64][68];   // Qt[d][qrow]
    __shared__ __align__(16) float Kt[64][68];   // Kt[d][kcol]
    __shared__ __align__(16) float Vs[64][68];   // Vs[krow][d]
    __shared__ __align__(16) float Pt[64][68];   // Pt[kcol][qrow] (S^T then P^T)
    __shared__ float alpha_s[64];
    __shared__ float l_s[64];

    const int tid = threadIdx.x;
    const int tx = tid & 15, ty = tid >> 4;
    const int qt = blockIdx.x;        // 0..15
    const int bh = blockIdx.y;        // 0..63
    const int bb = bh >> 3, h = bh & 7;

    const float* Q = qb + (size_t)bh * NSEQ * DH;
    const float* K = kb + (size_t)bh * NSEQ * DH;
    const float* V = vb + (size_t)bh * NSEQ * DH;

    // load Q tile transposed (tile is 16KB contiguous)
    {
        const float* Qbase = Q + (size_t)qt*64*DH;
#pragma unroll
        for (int u = 0; u < 4; u++) {
            int idx = tid + u*256;               // float4 index
            float4 fv = *(const float4*)(Qbase + idx*4);
            int row = idx >> 4, d0 = (idx & 15) * 4;
            Qt[d0+0][row] = fv.x; Qt[d0+1][row] = fv.y;
            Qt[d0+2][row] = fv.z; Qt[d0+3][row] = fv.w;
        }
    }

    float oacc[4][4] = {};
    float m_r = -1e30f, l_r = 0.f;   // valid for tid<64
    const float scale = 0.125f;

    for (int kt = 0; kt < 16; kt++) {
        __syncthreads();   // protect Kt/Vs/Pt from previous iteration's reads
        {
            const float* Kbase = K + (size_t)kt*64*DH;
            const float* Vbase = V + (size_t)kt*64*DH;
#pragma unroll
            for (int u = 0; u < 4; u++) {
                int idx = tid + u*256;
                float4 fv = *(const float4*)(Kbase + idx*4);
                int row = idx >> 4, d0 = (idx & 15) * 4;
                Kt[d0+0][row] = fv.x; Kt[d0+1][row] = fv.y;
                Kt[d0+2][row] = fv.z; Kt[d0+3][row] = fv.w;
                float4 vv = *(const float4*)(Vbase + idx*4);
                *(float4*)&Vs[row][d0] = vv;
            }
        }
        __syncthreads();

        // S^T = (Q K^T)^T, written scaled into Pt[kcol][qrow]
        float s[4][4] = {};
#pragma unroll 8
        for (int d = 0; d < 64; d++) {
            float a[4], b[4];
            *(float4*)a = *(const float4*)&Qt[d][ty*4];
            *(float4*)b = *(const float4*)&Kt[d][tx*4];
#pragma unroll
            for (int i = 0; i < 4; i++)
#pragma unroll
                for (int j = 0; j < 4; j++)
                    s[i][j] += a[i]*b[j];
        }
#pragma unroll
        for (int i = 0; i < 4; i++)
#pragma unroll
            for (int j = 0; j < 4; j++)
                Pt[tx*4+j][ty*4+i] = s[i][j]*scale;
        __syncthreads();

        // online softmax over rows (threads 0..63, one per q-row)
        if (tid < 64) {
            const int r = tid;
            float mloc = m_r;
            for (int j = 0; j < 64; j++) mloc = fmaxf(mloc, Pt[j][r]);
            const float al = __expf(m_r - mloc);
            float lsum = l_r * al;
            for (int j = 0; j < 64; j++) {
                float p = __expf(Pt[j][r] - mloc);
                Pt[j][r] = p;
                lsum += p;
            }
            m_r = mloc; l_r = lsum;
            alpha_s[r] = al;
        }
        __syncthreads();

        // rescale O, accumulate P·V
        float al[4];
#pragma unroll
        for (int i = 0; i < 4; i++) al[i] = alpha_s[ty*4+i];
#pragma unroll
        for (int i = 0; i < 4; i++)
#pragma unroll
            for (int j = 0; j < 4; j++)
                oacc[i][j] *= al[i];
#pragma unroll 8
        for (int kk = 0; kk < 64; kk++) {
            float a[4], b[4];
            *(float4*)a = *(const float4*)&Pt[kk][ty*4];
            *(float4*)b = *(const float4*)&Vs[kk][tx*4];
#pragma unroll
            for (int i = 0; i < 4; i++)
#pragma unroll
                for (int j = 0; j < 4; j++)
                    oacc[i][j] += a[i]*b[j];
        }
    }

    if (tid < 64) l_s[tid] = l_r;
    __syncthreads();

    // epilogue: normalize, inverse pose (o' = P_qinv o), merge heads
#pragma unroll
    for (int i = 0; i < 4; i++) {
        const int r = ty*4 + i;
        const int n = qt*64 + r;
        const float inv_l = 1.f / l_s[r];
        const float o0 = oacc[i][0]*inv_l, o1 = oacc[i][1]*inv_l;
        const float o2 = oacc[i][2]*inv_l, o3 = oacc[i][3]*inv_l;
        const float* R = rot   + (size_t)(bb*NSEQ + n)*9;
        const float* T = trans + (size_t)(bb*NSEQ + n)*3;
        const float ti0 = -(R[0]*T[0] + R[3]*T[1] + R[6]*T[2]);
        const float ti1 = -(R[1]*T[0] + R[4]*T[1] + R[7]*T[2]);
        const float ti2 = -(R[2]*T[0] + R[5]*T[1] + R[8]*T[2]);
        // o'[ii<3] = sum_j R[j][ii]*o_j + ti[ii]*o3 ; o'3 = o3
        const float p0 = R[0]*o0 + R[3]*o1 + R[6]*o2 + ti0*o3;
        const float p1 = R[1]*o0 + R[4]*o1 + R[7]*o2 + ti1*o3;
        const float p2 = R[2]*o0 + R[5]*o1 + R[8]*o2 + ti2*o3;
        const float p3 = o3;
        float4 ov = {p0, p1, p2, p3};
        *(float4*)(om + (size_t)(bb*NSEQ + n)*INNER + h*DH + tx*4) = ov;
    }
}

// ---------------------------------------------------------------------------
// Kernel 3: out = om @ w_out + b_out   [8192,512]x[512,512]
// ---------------------------------------------------------------------------
__global__ __launch_bounds__(256) void out_gemm_kernel(
    const float* __restrict__ A, const float* __restrict__ w,
    const float* __restrict__ bias, float* __restrict__ out)
{
    __shared__ __align__(16) float As[16][68];
    __shared__ __align__(16) float Bs[16][68];

    const int tid = threadIdx.x;
    const int tx = tid & 15, ty = tid >> 4;
    const int bx = blockIdx.x;   // feature tile (8)
    const int by = blockIdx.y;   // token tile (128)

    float acc[4][4] = {};

    const int arow = tid >> 2;
    const int akq  = (tid & 3) * 4;
    const int brow = tid >> 4;
    const int bc4  = (tid & 15) * 4;

    const float* xA = A + (size_t)(by*64 + arow)*INNER + akq;
    const float* wB = w + (size_t)brow*DIM + bx*64 + bc4;

    for (int k0 = 0; k0 < INNER; k0 += 16) {
        float4 av = *(const float4*)(xA + k0);
        As[akq+0][arow] = av.x; As[akq+1][arow] = av.y;
        As[akq+2][arow] = av.z; As[akq+3][arow] = av.w;
        *(float4*)&Bs[brow][bc4] = *(const float4*)(wB + (size_t)k0*DIM);
        __syncthreads();
#pragma unroll
        for (int kk = 0; kk < 16; kk++) {
            float a[4], b[4];
            *(float4*)a = *(const float4*)&As[kk][ty*4];
            *(float4*)b = *(const float4*)&Bs[kk][tx*4];
#pragma unroll
            for (int i = 0; i < 4; i++)
#pragma unroll
                for (int j = 0; j < 4; j++)
                    acc[i][j] += a[i]*b[j];
        }
        __syncthreads();
    }

    const int c0 = bx*64 + tx*4;
    const float bv0 = bias[c0+0], bv1 = bias[c0+1], bv2 = bias[c0+2], bv3 = bias[c0+3];
#pragma unroll
    for (int i = 0; i < 4; i++) {
        const int r = by*64 + ty*4 + i;
        float4 ov = {acc[i][0]+bv0, acc[i][1]+bv1, acc[i][2]+bv2, acc[i][3]+bv3};
        *(float4*)(out + (size_t)r*DIM + c0) = ov;
    }
}

extern "C" void kernel_launch(void* const* d_in, const int* in_sizes, int n_in,
                              void* d_out, int out_size, void* d_ws, size_t ws_size,
                              hipStream_t stream) {
    (void)in_sizes; (void)n_in; (void)out_size; (void)ws_size;
    const float* x     = (const float*)d_in[0];
    const float* rot   = (const float*)d_in[1];
    const float* trans = (const float*)d_in[2];
    const float* w_qkv = (const float*)d_in[3];
    const float* b_qkv = (const float*)d_in[4];
    const float* w_out = (const float*)d_in[5];
    const float* b_out = (const float*)d_in[6];
    float* out = (float*)d_out;

    float* ws = (float*)d_ws;
    const size_t HEADBUF = (size_t)BSZ*NH*NSEQ*DH;  // 4,194,304 floats
    float* qb = ws;
    float* kb = ws + HEADBUF;
    float* vb = ws + 2*HEADBUF;
    float* om = ws + 3*HEADBUF;                      // [B,N,INNER]

    qkv_pose_kernel<<<dim3(QKVN/64, NTOK/64), 256, 0, stream>>>(
        x, w_qkv, b_qkv, rot, trans, qb, kb, vb);
    attn_kernel<<<dim3(NSEQ/64, BSZ*NH), 256, 0, stream>>>(
        qb, kb, vb, rot, trans, om);
    out_gemm_kernel<<<dim3(DIM/64, NTOK/64), 256, 0, stream>>>(
        om, w_out, b_out, out);
}

// Round 2
// 415.675 us; speedup vs baseline: 1.4533x; 1.4533x over previous
//
#include <hip/hip_runtime.h>
#include <math.h>

#define BSZ   8
#define NSEQ  1024
#define DIM   512
#define NH    8
#define DH    64
#define INNER 512
#define NTOK  (BSZ*NSEQ)     // 8192
#define QKVN  (3*INNER)      // 1536

typedef __bf16 bf16x8 __attribute__((ext_vector_type(8)));
typedef float  f32x4  __attribute__((ext_vector_type(4)));

// q pre-scale: softmax scale (DH^-0.5 = 0.125) folded with log2(e) so the
// attention kernel can use raw exp2.
#define QSCL (0.125f * 1.44269504088896f)

static __device__ __forceinline__ ushort f2bf(float f) {
    union { float f; unsigned u; } v; v.f = f;
    unsigned r = (v.u + 0x7FFFu + ((v.u >> 16) & 1u)) >> 16;  // RNE
    return (ushort)r;
}

// ---------------------------------------------------------------------------
// Kernel 1: qkv = x @ w_qkv + b_qkv (fp32 GEMM), fused SE(3) pose transform,
// outputs q/k/v as bf16 in [B,H,N,DH]; q pre-scaled by QSCL.
// ---------------------------------------------------------------------------
__global__ __launch_bounds__(256) void qkv_pose_kernel(
    const float* __restrict__ x, const float* __restrict__ w,
    const float* __restrict__ bias, const float* __restrict__ rot,
    const float* __restrict__ trans,
    ushort* __restrict__ qb, ushort* __restrict__ kb, ushort* __restrict__ vb)
{
    __shared__ __align__(16) float As[16][68];  // As[k][row]
    __shared__ __align__(16) float Bs[16][68];  // Bs[k][col]

    const int tid = threadIdx.x;
    const int tx = tid & 15, ty = tid >> 4;
    const int bx = blockIdx.x;   // feature tile (24)
    const int by = blockIdx.y;   // token tile (128)

    float acc[4][4] = {};

    const int arow = tid >> 2;
    const int akq  = (tid & 3) * 4;
    const int brow = tid >> 4;
    const int bc4  = (tid & 15) * 4;

    const float* xA = x + (size_t)(by*64 + arow)*DIM + akq;
    const float* wB = w + (size_t)brow*QKVN + bx*64 + bc4;

    for (int k0 = 0; k0 < DIM; k0 += 16) {
        float4 av = *(const float4*)(xA + k0);
        As[akq+0][arow] = av.x; As[akq+1][arow] = av.y;
        As[akq+2][arow] = av.z; As[akq+3][arow] = av.w;
        *(float4*)&Bs[brow][bc4] = *(const float4*)(wB + (size_t)k0*QKVN);
        __syncthreads();
#pragma unroll
        for (int kk = 0; kk < 16; kk++) {
            float a[4], b[4];
            *(float4*)a = *(const float4*)&As[kk][ty*4];
            *(float4*)b = *(const float4*)&Bs[kk][tx*4];
#pragma unroll
            for (int i = 0; i < 4; i++)
#pragma unroll
                for (int j = 0; j < 4; j++)
                    acc[i][j] += a[i]*b[j];
        }
        __syncthreads();
    }

    const int c0  = bx*64 + tx*4;
    const int sec = c0 >> 9;        // 0=q 1=k 2=v
    const int f   = c0 & 511;
    const int h   = f >> 6;
    const int d   = f & 63;
    const float bv0 = bias[c0+0], bv1 = bias[c0+1], bv2 = bias[c0+2], bv3 = bias[c0+3];

#pragma unroll
    for (int i = 0; i < 4; i++) {
        const int r  = by*64 + ty*4 + i;
        const int bb = r >> 10;
        const int n  = r & 1023;
        const float* R = rot   + (size_t)(bb*NSEQ + n)*9;
        const float* T = trans + (size_t)(bb*NSEQ + n)*3;
        const float g0 = acc[i][0]+bv0, g1 = acc[i][1]+bv1;
        const float g2 = acc[i][2]+bv2, g3 = acc[i][3]+bv3;
        float o0, o1, o2, o3;
        if (sec == 0) {
            o0 = R[0]*g0 + R[1]*g1 + R[2]*g2;
            o1 = R[3]*g0 + R[4]*g1 + R[5]*g2;
            o2 = R[6]*g0 + R[7]*g1 + R[8]*g2;
            const float ti0 = -(R[0]*T[0] + R[3]*T[1] + R[6]*T[2]);
            const float ti1 = -(R[1]*T[0] + R[4]*T[1] + R[7]*T[2]);
            const float ti2 = -(R[2]*T[0] + R[5]*T[1] + R[8]*T[2]);
            o3 = ti0*g0 + ti1*g1 + ti2*g2 + g3;
            o0 *= QSCL; o1 *= QSCL; o2 *= QSCL; o3 *= QSCL;
        } else {
            o0 = R[0]*g0 + R[1]*g1 + R[2]*g2 + T[0]*g3;
            o1 = R[3]*g0 + R[4]*g1 + R[5]*g2 + T[1]*g3;
            o2 = R[6]*g0 + R[7]*g1 + R[8]*g2 + T[2]*g3;
            o3 = g3;
        }
        ushort* dst = (sec == 0 ? qb : (sec == 1 ? kb : vb))
                      + ((size_t)((bb*NH + h)*NSEQ + n))*DH + d;
        ushort4 ov = { f2bf(o0), f2bf(o1), f2bf(o2), f2bf(o3) };
        *(ushort4*)dst = ov;
    }
}

// ---------------------------------------------------------------------------
// Kernel 2: MFMA flash attention. Block = 4 waves, 64 Q rows (16/wave),
// K-tiles of 64. QK^T and PV on mfma_f32_16x16x32_bf16; in-register online
// softmax (shfl_xor over the 16-lane column group); P via per-wave LDS
// round-trip (C/D layout -> A layout); V staged transposed in LDS.
// Epilogue: O -> LDS -> SE(3) inverse pose -> om (fp32, [B,N,INNER]).
// ---------------------------------------------------------------------------
__global__ __launch_bounds__(256) void attn_mfma_kernel(
    const ushort* __restrict__ qb, const ushort* __restrict__ kb,
    const ushort* __restrict__ vb, const float* __restrict__ rot,
    const float* __restrict__ trans, float* __restrict__ om)
{
    // LDS carve: Ks 64x72 bf16 (9216B) | Vt 64x72 bf16 (9216B) | Ps 4x16x72 (9216B)
    // Epilogue overlays Osh[64][68] fp32 (17408B) on Ks+Vt region.
    __shared__ __align__(16) char smem[27648];
    ushort (*Ks)[72] = (ushort (*)[72])(smem);
    ushort (*Vt)[72] = (ushort (*)[72])(smem + 9216);

    const int tid  = threadIdx.x;
    const int lane = tid & 63;
    const int w    = tid >> 6;         // wave 0..3
    const int c    = lane & 15;        // column-in-16 / A-row m
    const int quad = lane >> 4;        // 0..3

    ushort (*Psw)[72] = (ushort (*)[72])(smem + 18432 + w*2304); // [16][72]

    const int qt = blockIdx.x;         // 0..15
    const int bh = blockIdx.y;         // 0..63
    const int bb = bh >> 3, h = bh & 7;

    const ushort* Q = qb + (size_t)bh * NSEQ * DH;
    const ushort* K = kb + (size_t)bh * NSEQ * DH;
    const ushort* V = vb + (size_t)bh * NSEQ * DH;

    // Q fragments (A-layout): row m=c of this wave's 16, k = kc*32 + quad*8 + j
    bf16x8 qf0, qf1;
    {
        const ushort* qrow = Q + (size_t)(qt*64 + w*16 + c)*DH + quad*8;
        qf0 = *(const bf16x8*)(qrow);
        qf1 = *(const bf16x8*)(qrow + 32);
    }

    f32x4 Oacc[4] = {};                 // per n-tile (d16-tile)
    float mreg[4], lreg[4];
#pragma unroll
    for (int r = 0; r < 4; r++) { mreg[r] = -1e30f; lreg[r] = 0.f; }

    const int skey = lane;              // staging: key = lane

    for (int kt = 0; kt < 16; kt++) {
        __syncthreads();
        {
            const ushort* Kb = K + (size_t)kt*64*DH;
            const ushort* Vb = V + (size_t)kt*64*DH;
#pragma unroll
            for (int u = 0; u < 2; u++) {
                const int d0 = (w + 4*u) * 8;   // this wave's d-chunk
                *(uint4*)&Ks[skey][d0] = *(const uint4*)(Kb + skey*DH + d0);
                union { uint4 v; ushort u16[8]; } t;
                t.v = *(const uint4*)(Vb + skey*DH + d0);
#pragma unroll
                for (int i = 0; i < 8; i++) Vt[d0+i][skey] = t.u16[i];
            }
        }
        __syncthreads();

        // S = Q K^T  (rows = this wave's 16 q-rows, cols = 64 keys)
        f32x4 s[4];
#pragma unroll
        for (int nt = 0; nt < 4; nt++) {
            const ushort* kr = &Ks[nt*16 + c][quad*8];
            bf16x8 b0 = *(const bf16x8*)(kr);
            bf16x8 b1 = *(const bf16x8*)(kr + 32);
            f32x4 acc = {0.f, 0.f, 0.f, 0.f};
            acc = __builtin_amdgcn_mfma_f32_16x16x32_bf16(qf0, b0, acc, 0, 0, 0);
            acc = __builtin_amdgcn_mfma_f32_16x16x32_bf16(qf1, b1, acc, 0, 0, 0);
            s[nt] = acc;
        }

        // ---- online softmax, fully in-register ----
        float rmax[4];
#pragma unroll
        for (int r = 0; r < 4; r++)
            rmax[r] = fmaxf(fmaxf(s[0][r], s[1][r]), fmaxf(s[2][r], s[3][r]));
#pragma unroll
        for (int mk = 1; mk < 16; mk <<= 1)
#pragma unroll
            for (int r = 0; r < 4; r++)
                rmax[r] = fmaxf(rmax[r], __shfl_xor(rmax[r], mk));

        float alpha[4], rsum[4];
#pragma unroll
        for (int r = 0; r < 4; r++) {
            const float mn = fmaxf(mreg[r], rmax[r]);
            alpha[r] = exp2f(mreg[r] - mn);
            mreg[r]  = mn;
            rsum[r]  = 0.f;
        }
        float pv[4][4];
#pragma unroll
        for (int nt = 0; nt < 4; nt++)
#pragma unroll
            for (int r = 0; r < 4; r++) {
                const float p = exp2f(s[nt][r] - mreg[r]);
                pv[nt][r] = p;
                rsum[r] += p;
            }
#pragma unroll
        for (int mk = 1; mk < 16; mk <<= 1)
#pragma unroll
            for (int r = 0; r < 4; r++)
                rsum[r] += __shfl_xor(rsum[r], mk);
#pragma unroll
        for (int r = 0; r < 4; r++)
            lreg[r] = lreg[r]*alpha[r] + rsum[r];
#pragma unroll
        for (int nt = 0; nt < 4; nt++)
#pragma unroll
            for (int r = 0; r < 4; r++)
                Oacc[nt][r] *= alpha[r];

        // P (C/D layout) -> LDS as bf16
#pragma unroll
        for (int nt = 0; nt < 4; nt++)
#pragma unroll
            for (int r = 0; r < 4; r++)
                Psw[quad*4 + r][nt*16 + c] = f2bf(pv[nt][r]);
        __asm__ volatile("s_waitcnt lgkmcnt(0)" ::: "memory");

        // O += P V  (P re-read in A-layout, V from transposed LDS in B-layout)
#pragma unroll
        for (int kc = 0; kc < 2; kc++) {
            bf16x8 a = *(const bf16x8*)&Psw[c][kc*32 + quad*8];
#pragma unroll
            for (int nt = 0; nt < 4; nt++) {
                bf16x8 b = *(const bf16x8*)&Vt[nt*16 + c][kc*32 + quad*8];
                Oacc[nt] = __builtin_amdgcn_mfma_f32_16x16x32_bf16(a, b, Oacc[nt], 0, 0, 0);
            }
        }
    }

    // normalize and stage O to LDS (overlay on Ks/Vt region)
    __syncthreads();
    float (*Osh)[68] = (float (*)[68])(smem);   // [64][68]
    {
        float inv[4];
#pragma unroll
        for (int r = 0; r < 4; r++) inv[r] = 1.f / lreg[r];
#pragma unroll
        for (int nt = 0; nt < 4; nt++)
#pragma unroll
            for (int r = 0; r < 4; r++)
                Osh[w*16 + quad*4 + r][nt*16 + c] = Oacc[nt][r] * inv[r];
    }
    __syncthreads();

    // epilogue: inverse pose (o' = P_qinv o) on groups of 4, merge heads
#pragma unroll
    for (int u = 0; u < 4; u++) {
        const int t   = tid + u*256;       // 0..1023
        const int row = t >> 4;            // 0..63
        const int g   = t & 15;            // d-group
        const int n   = qt*64 + row;
        const float o0 = Osh[row][g*4+0], o1 = Osh[row][g*4+1];
        const float o2 = Osh[row][g*4+2], o3 = Osh[row][g*4+3];
        const float* R = rot   + (size_t)(bb*NSEQ + n)*9;
        const float* T = trans + (size_t)(bb*NSEQ + n)*3;
        const float ti0 = -(R[0]*T[0] + R[3]*T[1] + R[6]*T[2]);
        const float ti1 = -(R[1]*T[0] + R[4]*T[1] + R[7]*T[2]);
        const float ti2 = -(R[2]*T[0] + R[5]*T[1] + R[8]*T[2]);
        const float p0 = R[0]*o0 + R[3]*o1 + R[6]*o2 + ti0*o3;
        const float p1 = R[1]*o0 + R[4]*o1 + R[7]*o2 + ti1*o3;
        const float p2 = R[2]*o0 + R[5]*o1 + R[8]*o2 + ti2*o3;
        const float p3 = o3;
        float4 ov = {p0, p1, p2, p3};
        *(float4*)(om + (size_t)(bb*NSEQ + n)*INNER + h*DH + g*4) = ov;
    }
}

// ---------------------------------------------------------------------------
// Kernel 3: out = om @ w_out + b_out   [8192,512]x[512,512]  (fp32)
// ---------------------------------------------------------------------------
__global__ __launch_bounds__(256) void out_gemm_kernel(
    const float* __restrict__ A, const float* __restrict__ w,
    const float* __restrict__ bias, float* __restrict__ out)
{
    __shared__ __align__(16) float As[16][68];
    __shared__ __align__(16) float Bs[16][68];

    const int tid = threadIdx.x;
    const int tx = tid & 15, ty = tid >> 4;
    const int bx = blockIdx.x;
    const int by = blockIdx.y;

    float acc[4][4] = {};

    const int arow = tid >> 2;
    const int akq  = (tid & 3) * 4;
    const int brow = tid >> 4;
    const int bc4  = (tid & 15) * 4;

    const float* xA = A + (size_t)(by*64 + arow)*INNER + akq;
    const float* wB = w + (size_t)brow*DIM + bx*64 + bc4;

    for (int k0 = 0; k0 < INNER; k0 += 16) {
        float4 av = *(const float4*)(xA + k0);
        As[akq+0][arow] = av.x; As[akq+1][arow] = av.y;
        As[akq+2][arow] = av.z; As[akq+3][arow] = av.w;
        *(float4*)&Bs[brow][bc4] = *(const float4*)(wB + (size_t)k0*DIM);
        __syncthreads();
#pragma unroll
        for (int kk = 0; kk < 16; kk++) {
            float a[4], b[4];
            *(float4*)a = *(const float4*)&As[kk][ty*4];
            *(float4*)b = *(const float4*)&Bs[kk][tx*4];
#pragma unroll
            for (int i = 0; i < 4; i++)
#pragma unroll
                for (int j = 0; j < 4; j++)
                    acc[i][j] += a[i]*b[j];
        }
        __syncthreads();
    }

    const int c0 = bx*64 + tx*4;
    const float bv0 = bias[c0+0], bv1 = bias[c0+1], bv2 = bias[c0+2], bv3 = bias[c0+3];
#pragma unroll
    for (int i = 0; i < 4; i++) {
        const int r = by*64 + ty*4 + i;
        float4 ov = {acc[i][0]+bv0, acc[i][1]+bv1, acc[i][2]+bv2, acc[i][3]+bv3};
        *(float4*)(out + (size_t)r*DIM + c0) = ov;
    }
}

extern "C" void kernel_launch(void* const* d_in, const int* in_sizes, int n_in,
                              void* d_out, int out_size, void* d_ws, size_t ws_size,
                              hipStream_t stream) {
    (void)in_sizes; (void)n_in; (void)out_size; (void)ws_size;
    const float* x     = (const float*)d_in[0];
    const float* rot   = (const float*)d_in[1];
    const float* trans = (const float*)d_in[2];
    const float* w_qkv = (const float*)d_in[3];
    const float* b_qkv = (const float*)d_in[4];
    const float* w_out = (const float*)d_in[5];
    const float* b_out = (const float*)d_in[6];
    float* out = (float*)d_out;

    const size_t HEADBUF = (size_t)BSZ*NH*NSEQ*DH;   // 4,194,304 elements
    ushort* qb = (ushort*)d_ws;
    ushort* kb = qb + HEADBUF;
    ushort* vb = kb + HEADBUF;
    float*  om = (float*)(vb + HEADBUF);             // [B,N,INNER] fp32

    qkv_pose_kernel<<<dim3(QKVN/64, NTOK/64), 256, 0, stream>>>(
        x, w_qkv, b_qkv, rot, trans, qb, kb, vb);
    attn_mfma_kernel<<<dim3(NSEQ/64, BSZ*NH), 256, 0, stream>>>(
        qb, kb, vb, rot, trans, om);
    out_gemm_kernel<<<dim3(DIM/64, NTOK/64), 256, 0, stream>>>(
        om, w_out, b_out, out);
}

// Round 5
// 242.431 us; speedup vs baseline: 2.4918x; 1.7146x over previous
//
#include <hip/hip_runtime.h>
#include <math.h>

#define BSZ   8
#define NSEQ  1024
#define DIM   512
#define NH    8
#define DH    64
#define INNER 512
#define NTOK  (BSZ*NSEQ)     // 8192
#define QKVN  (3*INNER)      // 1536

typedef __bf16 bf16x8 __attribute__((ext_vector_type(8)));
typedef float  f32x4  __attribute__((ext_vector_type(4)));

// q pre-scale: softmax scale (DH^-0.5 = 0.125) folded with log2(e)
#define QSCL (0.125f * 1.44269504088896f)

static __device__ __forceinline__ ushort f2bf(float f) {
    union { float f; unsigned u; } v; v.f = f;
    unsigned r = (v.u + 0x7FFFu + ((v.u >> 16) & 1u)) >> 16;  // RNE
    return (ushort)r;
}
static __device__ __forceinline__ float bf2f(ushort u) {
    union { unsigned u; float f; } v; v.u = ((unsigned)u) << 16;
    return v.f;
}
static __device__ __forceinline__ void split2(float x, ushort& h, ushort& l) {
    h = f2bf(x);
    l = f2bf(x - bf2f(h));
}

// ---------------------------------------------------------------------------
// Elementwise fp32 -> bf16 hi/lo split (x)
// ---------------------------------------------------------------------------
__global__ __launch_bounds__(256) void split_cvt_kernel(
    const float* __restrict__ in, ushort* __restrict__ oh, ushort* __restrict__ ol)
{
    const int i = blockIdx.x * 256 + threadIdx.x;
    float4 v = ((const float4*)in)[i];
    ushort4 h, l;
    split2(v.x, h.x, l.x); split2(v.y, h.y, l.y);
    split2(v.z, h.z, l.z); split2(v.w, h.w, l.w);
    ((ushort4*)oh)[i] = h;
    ((ushort4*)ol)[i] = l;
}

// ---------------------------------------------------------------------------
// Transpose + split: in [K][F] fp32 row-major -> outh/outl [F][K] bf16
// ---------------------------------------------------------------------------
__global__ __launch_bounds__(256) void tconv_split_kernel(
    const float* __restrict__ in, ushort* __restrict__ outh,
    ushort* __restrict__ outl, int K, int F)
{
    __shared__ float tile[32][33];
    const int bx = blockIdx.x;           // F/32
    const int by = blockIdx.y;           // K/32
    const int lx = threadIdx.x & 31, ly = threadIdx.x >> 5;
#pragma unroll
    for (int u = 0; u < 4; u++) {
        const int k = by*32 + ly + u*8;
        tile[ly + u*8][lx] = in[(size_t)k*F + bx*32 + lx];
    }
    __syncthreads();
#pragma unroll
    for (int u = 0; u < 4; u++) {
        const int f = bx*32 + ly + u*8;
        ushort h, l;
        split2(tile[lx][ly + u*8], h, l);
        outh[(size_t)f*K + by*32 + lx] = h;
        outl[(size_t)f*K + by*32 + lx] = l;
    }
}

// ---------------------------------------------------------------------------
// Kernel 1: qkv^T split-bf16 MFMA GEMM (fp32-accurate).
// C^T[feat][tok] = (Ah+Al)[feat][k] * (Bh+Bl)[tok][k], 3 MFMA passes.
// 128x128 tile, KC=32; epilogue: bias + SE(3) pose -> bf16 q/k/v [B,H,N,DH].
// ---------------------------------------------------------------------------
__global__ __launch_bounds__(256) void qkv_gemm_split(
    const ushort* __restrict__ Agh, const ushort* __restrict__ Agl,
    const ushort* __restrict__ Bgh, const ushort* __restrict__ Bgl,
    const float* __restrict__ bias, const float* __restrict__ rot,
    const float* __restrict__ trans,
    ushort* __restrict__ qb, ushort* __restrict__ kb, ushort* __restrict__ vb)
{
    __shared__ __align__(16) ushort Ah[128][40];
    __shared__ __align__(16) ushort Al[128][40];
    __shared__ __align__(16) ushort Bh[128][40];
    __shared__ __align__(16) ushort Bl[128][40];

    const int tid  = threadIdx.x;
    const int lane = tid & 63;
    const int w    = tid >> 6;
    const int c    = lane & 15;
    const int quad = lane >> 4;
    const int wr   = w >> 1, wc = w & 1;
    const int tn   = blockIdx.x;   // token tile (64)
    const int tf   = blockIdx.y;   // feature tile (12)

    f32x4 acc[4][4] = {};

    const int sr = tid >> 1;             // staging row 0..127
    const int sj = (tid & 1) * 16;       // staging k-offset 0/16
    const ushort* pAh = Agh + (size_t)(tf*128 + sr)*DIM + sj;
    const ushort* pAl = Agl + (size_t)(tf*128 + sr)*DIM + sj;
    const ushort* pBh = Bgh + (size_t)(tn*128 + sr)*DIM + sj;
    const ushort* pBl = Bgl + (size_t)(tn*128 + sr)*DIM + sj;

    for (int k0 = 0; k0 < DIM; k0 += 32) {
        uint4 ah0 = *(const uint4*)(pAh + k0);
        uint4 ah1 = *(const uint4*)(pAh + k0 + 8);
        uint4 al0 = *(const uint4*)(pAl + k0);
        uint4 al1 = *(const uint4*)(pAl + k0 + 8);
        uint4 bh0 = *(const uint4*)(pBh + k0);
        uint4 bh1 = *(const uint4*)(pBh + k0 + 8);
        uint4 bl0 = *(const uint4*)(pBl + k0);
        uint4 bl1 = *(const uint4*)(pBl + k0 + 8);
        __syncthreads();
        *(uint4*)&Ah[sr][sj+0] = ah0;  *(uint4*)&Ah[sr][sj+8] = ah1;
        *(uint4*)&Al[sr][sj+0] = al0;  *(uint4*)&Al[sr][sj+8] = al1;
        *(uint4*)&Bh[sr][sj+0] = bh0;  *(uint4*)&Bh[sr][sj+8] = bh1;
        *(uint4*)&Bl[sr][sj+0] = bl0;  *(uint4*)&Bl[sr][sj+8] = bl1;
        __syncthreads();

        bf16x8 fah[4], fal[4], fbh[4], fbl[4];
#pragma unroll
        for (int i = 0; i < 4; i++) {
            fah[i] = *(const bf16x8*)&Ah[wr*64 + i*16 + c][quad*8];
            fal[i] = *(const bf16x8*)&Al[wr*64 + i*16 + c][quad*8];
        }
#pragma unroll
        for (int j = 0; j < 4; j++) {
            fbh[j] = *(const bf16x8*)&Bh[wc*64 + j*16 + c][quad*8];
            fbl[j] = *(const bf16x8*)&Bl[wc*64 + j*16 + c][quad*8];
        }
#pragma unroll
        for (int i = 0; i < 4; i++)
#pragma unroll
            for (int j = 0; j < 4; j++) {
                acc[i][j] = __builtin_amdgcn_mfma_f32_16x16x32_bf16(
                    fah[i], fbh[j], acc[i][j], 0, 0, 0);
                acc[i][j] = __builtin_amdgcn_mfma_f32_16x16x32_bf16(
                    fah[i], fbl[j], acc[i][j], 0, 0, 0);
                acc[i][j] = __builtin_amdgcn_mfma_f32_16x16x32_bf16(
                    fal[i], fbh[j], acc[i][j], 0, 0, 0);
            }
    }

    // epilogue: bias + SE(3) pose + scatter (verified mapping from R2/R3)
    const int sec = tf >> 2;          // 0=q 1=k 2=v (block-uniform)
    ushort* dstbuf = (sec == 0) ? qb : ((sec == 1) ? kb : vb);

#pragma unroll
    for (int j = 0; j < 4; j++) {
        const int tc = tn*128 + wc*64 + j*16 + c;
        const int bb = tc >> 10, n = tc & 1023;
        const float* R = rot   + (size_t)(bb*NSEQ + n)*9;
        const float* T = trans + (size_t)(bb*NSEQ + n)*3;
        const float R0=R[0],R1=R[1],R2=R[2],R3=R[3],R4=R[4],R5=R[5],R6=R[6],R7=R[7],R8=R[8];
        const float T0=T[0],T1=T[1],T2=T[2];
        float ti0 = 0.f, ti1 = 0.f, ti2 = 0.f;
        if (sec == 0) {
            ti0 = -(R0*T0 + R3*T1 + R6*T2);
            ti1 = -(R1*T0 + R4*T1 + R7*T2);
            ti2 = -(R2*T0 + R5*T1 + R8*T2);
        }
#pragma unroll
        for (int i = 0; i < 4; i++) {
            const int fr = tf*128 + wr*64 + i*16 + quad*4;
            const int fl = fr & 511;
            const int h  = fl >> 6, d = fl & 63;
            float4 bv = *(const float4*)(bias + fr);
            const float g0 = acc[i][j][0] + bv.x;
            const float g1 = acc[i][j][1] + bv.y;
            const float g2 = acc[i][j][2] + bv.z;
            const float g3 = acc[i][j][3] + bv.w;
            float o0, o1, o2, o3;
            if (sec == 0) {
                o0 = (R0*g0 + R1*g1 + R2*g2) * QSCL;
                o1 = (R3*g0 + R4*g1 + R5*g2) * QSCL;
                o2 = (R6*g0 + R7*g1 + R8*g2) * QSCL;
                o3 = (ti0*g0 + ti1*g1 + ti2*g2 + g3) * QSCL;
            } else {
                o0 = R0*g0 + R1*g1 + R2*g2 + T0*g3;
                o1 = R3*g0 + R4*g1 + R5*g2 + T1*g3;
                o2 = R6*g0 + R7*g1 + R8*g2 + T2*g3;
                o3 = g3;
            }
            ushort4 ov = { f2bf(o0), f2bf(o1), f2bf(o2), f2bf(o3) };
            *(ushort4*)(dstbuf + ((size_t)((bb*NH + h)*NSEQ + n))*DH + d) = ov;
        }
    }
}

// ---------------------------------------------------------------------------
// Kernel 2: MFMA flash attention — R2-verified bf16 core; epilogue writes
// om as split hi/lo bf16 pairs (fp32-accurate handoff to the out-GEMM).
// ---------------------------------------------------------------------------
__global__ __launch_bounds__(256) void attn_mfma_kernel(
    const ushort* __restrict__ qb, const ushort* __restrict__ kb,
    const ushort* __restrict__ vb, const float* __restrict__ rot,
    const float* __restrict__ trans,
    ushort* __restrict__ omh, ushort* __restrict__ oml)
{
    __shared__ __align__(16) char smem[27648];
    ushort (*Ks)[72] = (ushort (*)[72])(smem);
    ushort (*Vt)[72] = (ushort (*)[72])(smem + 9216);

    const int tid  = threadIdx.x;
    const int lane = tid & 63;
    const int w    = tid >> 6;
    const int c    = lane & 15;
    const int quad = lane >> 4;

    ushort (*Psw)[72] = (ushort (*)[72])(smem + 18432 + w*2304);

    const int qt = blockIdx.x;
    const int bh = blockIdx.y;
    const int bb = bh >> 3, h = bh & 7;

    const ushort* Q = qb + (size_t)bh * NSEQ * DH;
    const ushort* K = kb + (size_t)bh * NSEQ * DH;
    const ushort* V = vb + (size_t)bh * NSEQ * DH;

    bf16x8 qf0, qf1;
    {
        const ushort* qrow = Q + (size_t)(qt*64 + w*16 + c)*DH + quad*8;
        qf0 = *(const bf16x8*)(qrow);
        qf1 = *(const bf16x8*)(qrow + 32);
    }

    f32x4 Oacc[4] = {};
    float mreg[4], lreg[4];
#pragma unroll
    for (int r = 0; r < 4; r++) { mreg[r] = -1e30f; lreg[r] = 0.f; }

    const int skey = lane;

    for (int kt = 0; kt < 16; kt++) {
        __syncthreads();
        {
            const ushort* Kb = K + (size_t)kt*64*DH;
            const ushort* Vb = V + (size_t)kt*64*DH;
#pragma unroll
            for (int u = 0; u < 2; u++) {
                const int d0 = (w + 4*u) * 8;
                *(uint4*)&Ks[skey][d0] = *(const uint4*)(Kb + skey*DH + d0);
                union { uint4 v; ushort u16[8]; } t;
                t.v = *(const uint4*)(Vb + skey*DH + d0);
#pragma unroll
                for (int i = 0; i < 8; i++) Vt[d0+i][skey] = t.u16[i];
            }
        }
        __syncthreads();

        f32x4 s[4];
#pragma unroll
        for (int nt = 0; nt < 4; nt++) {
            const ushort* kr = &Ks[nt*16 + c][quad*8];
            bf16x8 b0 = *(const bf16x8*)(kr);
            bf16x8 b1 = *(const bf16x8*)(kr + 32);
            f32x4 a = {0.f, 0.f, 0.f, 0.f};
            a = __builtin_amdgcn_mfma_f32_16x16x32_bf16(qf0, b0, a, 0, 0, 0);
            a = __builtin_amdgcn_mfma_f32_16x16x32_bf16(qf1, b1, a, 0, 0, 0);
            s[nt] = a;
        }

        float rmax[4];
#pragma unroll
        for (int r = 0; r < 4; r++)
            rmax[r] = fmaxf(fmaxf(s[0][r], s[1][r]), fmaxf(s[2][r], s[3][r]));
#pragma unroll
        for (int mk = 1; mk < 16; mk <<= 1)
#pragma unroll
            for (int r = 0; r < 4; r++)
                rmax[r] = fmaxf(rmax[r], __shfl_xor(rmax[r], mk));

        float alpha[4], rsum[4];
#pragma unroll
        for (int r = 0; r < 4; r++) {
            const float mn = fmaxf(mreg[r], rmax[r]);
            alpha[r] = exp2f(mreg[r] - mn);
            mreg[r]  = mn;
            rsum[r]  = 0.f;
        }
        float pv[4][4];
#pragma unroll
        for (int nt = 0; nt < 4; nt++)
#pragma unroll
            for (int r = 0; r < 4; r++) {
                const float p = exp2f(s[nt][r] - mreg[r]);
                pv[nt][r] = p;
                rsum[r] += p;
            }
#pragma unroll
        for (int mk = 1; mk < 16; mk <<= 1)
#pragma unroll
            for (int r = 0; r < 4; r++)
                rsum[r] += __shfl_xor(rsum[r], mk);
#pragma unroll
        for (int r = 0; r < 4; r++)
            lreg[r] = lreg[r]*alpha[r] + rsum[r];
#pragma unroll
        for (int nt = 0; nt < 4; nt++)
#pragma unroll
            for (int r = 0; r < 4; r++)
                Oacc[nt][r] *= alpha[r];

#pragma unroll
        for (int nt = 0; nt < 4; nt++)
#pragma unroll
            for (int r = 0; r < 4; r++)
                Psw[quad*4 + r][nt*16 + c] = f2bf(pv[nt][r]);
        __asm__ volatile("s_waitcnt lgkmcnt(0)" ::: "memory");

#pragma unroll
        for (int kc = 0; kc < 2; kc++) {
            bf16x8 a = *(const bf16x8*)&Psw[c][kc*32 + quad*8];
#pragma unroll
            for (int nt = 0; nt < 4; nt++) {
                bf16x8 b = *(const bf16x8*)&Vt[nt*16 + c][kc*32 + quad*8];
                Oacc[nt] = __builtin_amdgcn_mfma_f32_16x16x32_bf16(a, b, Oacc[nt], 0, 0, 0);
            }
        }
    }

    __syncthreads();
    float (*Osh)[68] = (float (*)[68])(smem);
    {
        float inv[4];
#pragma unroll
        for (int r = 0; r < 4; r++) inv[r] = 1.f / lreg[r];
#pragma unroll
        for (int nt = 0; nt < 4; nt++)
#pragma unroll
            for (int r = 0; r < 4; r++)
                Osh[w*16 + quad*4 + r][nt*16 + c] = Oacc[nt][r] * inv[r];
    }
    __syncthreads();

#pragma unroll
    for (int u = 0; u < 4; u++) {
        const int t   = tid + u*256;
        const int row = t >> 4;
        const int g   = t & 15;
        const int n   = qt*64 + row;
        const float o0 = Osh[row][g*4+0], o1 = Osh[row][g*4+1];
        const float o2 = Osh[row][g*4+2], o3 = Osh[row][g*4+3];
        const float* R = rot   + (size_t)(bb*NSEQ + n)*9;
        const float* T = trans + (size_t)(bb*NSEQ + n)*3;
        const float ti0 = -(R[0]*T[0] + R[3]*T[1] + R[6]*T[2]);
        const float ti1 = -(R[1]*T[0] + R[4]*T[1] + R[7]*T[2]);
        const float ti2 = -(R[2]*T[0] + R[5]*T[1] + R[8]*T[2]);
        const float p0 = R[0]*o0 + R[3]*o1 + R[6]*o2 + ti0*o3;
        const float p1 = R[1]*o0 + R[4]*o1 + R[7]*o2 + ti1*o3;
        const float p2 = R[2]*o0 + R[5]*o1 + R[8]*o2 + ti2*o3;
        const float p3 = o3;
        ushort4 hv, lv;
        split2(p0, hv.x, lv.x); split2(p1, hv.y, lv.y);
        split2(p2, hv.z, lv.z); split2(p3, hv.w, lv.w);
        const size_t idx = (size_t)(bb*NSEQ + n)*INNER + h*DH + g*4;
        *(ushort4*)(omh + idx) = hv;
        *(ushort4*)(oml + idx) = lv;
    }
}

// ---------------------------------------------------------------------------
// Kernel 3: out^T split-bf16 MFMA GEMM (fp32-accurate).
// C^T[feat][tok] = (woTh+woTl)[feat][k] * (omh+oml)[tok][k]; + bias -> fp32.
// ---------------------------------------------------------------------------
__global__ __launch_bounds__(256) void out_gemm_split(
    const ushort* __restrict__ Agh, const ushort* __restrict__ Agl,
    const ushort* __restrict__ Bgh, const ushort* __restrict__ Bgl,
    const float* __restrict__ bias, float* __restrict__ out)
{
    __shared__ __align__(16) ushort Ah[128][40];
    __shared__ __align__(16) ushort Al[128][40];
    __shared__ __align__(16) ushort Bh[128][40];
    __shared__ __align__(16) ushort Bl[128][40];

    const int tid  = threadIdx.x;
    const int lane = tid & 63;
    const int w    = tid >> 6;
    const int c    = lane & 15;
    const int quad = lane >> 4;
    const int wr   = w >> 1, wc = w & 1;
    const int tn   = blockIdx.x;   // token tile (64)
    const int tf   = blockIdx.y;   // feature tile (4)

    f32x4 acc[4][4] = {};

    const int sr = tid >> 1;
    const int sj = (tid & 1) * 16;
    const ushort* pAh = Agh + (size_t)(tf*128 + sr)*INNER + sj;
    const ushort* pAl = Agl + (size_t)(tf*128 + sr)*INNER + sj;
    const ushort* pBh = Bgh + (size_t)(tn*128 + sr)*INNER + sj;
    const ushort* pBl = Bgl + (size_t)(tn*128 + sr)*INNER + sj;

    for (int k0 = 0; k0 < INNER; k0 += 32) {
        uint4 ah0 = *(const uint4*)(pAh + k0);
        uint4 ah1 = *(const uint4*)(pAh + k0 + 8);
        uint4 al0 = *(const uint4*)(pAl + k0);
        uint4 al1 = *(const uint4*)(pAl + k0 + 8);
        uint4 bh0 = *(const uint4*)(pBh + k0);
        uint4 bh1 = *(const uint4*)(pBh + k0 + 8);
        uint4 bl0 = *(const uint4*)(pBl + k0);
        uint4 bl1 = *(const uint4*)(pBl + k0 + 8);
        __syncthreads();
        *(uint4*)&Ah[sr][sj+0] = ah0;  *(uint4*)&Ah[sr][sj+8] = ah1;
        *(uint4*)&Al[sr][sj+0] = al0;  *(uint4*)&Al[sr][sj+8] = al1;
        *(uint4*)&Bh[sr][sj+0] = bh0;  *(uint4*)&Bh[sr][sj+8] = bh1;
        *(uint4*)&Bl[sr][sj+0] = bl0;  *(uint4*)&Bl[sr][sj+8] = bl1;
        __syncthreads();

        bf16x8 fah[4], fal[4], fbh[4], fbl[4];
#pragma unroll
        for (int i = 0; i < 4; i++) {
            fah[i] = *(const bf16x8*)&Ah[wr*64 + i*16 + c][quad*8];
            fal[i] = *(const bf16x8*)&Al[wr*64 + i*16 + c][quad*8];
        }
#pragma unroll
        for (int j = 0; j < 4; j++) {
            fbh[j] = *(const bf16x8*)&Bh[wc*64 + j*16 + c][quad*8];
            fbl[j] = *(const bf16x8*)&Bl[wc*64 + j*16 + c][quad*8];
        }
#pragma unroll
        for (int i = 0; i < 4; i++)
#pragma unroll
            for (int j = 0; j < 4; j++) {
                acc[i][j] = __builtin_amdgcn_mfma_f32_16x16x32_bf16(
                    fah[i], fbh[j], acc[i][j], 0, 0, 0);
                acc[i][j] = __builtin_amdgcn_mfma_f32_16x16x32_bf16(
                    fah[i], fbl[j], acc[i][j], 0, 0, 0);
                acc[i][j] = __builtin_amdgcn_mfma_f32_16x16x32_bf16(
                    fal[i], fbh[j], acc[i][j], 0, 0, 0);
            }
    }

#pragma unroll
    for (int j = 0; j < 4; j++) {
        const int tc = tn*128 + wc*64 + j*16 + c;
#pragma unroll
        for (int i = 0; i < 4; i++) {
            const int fr = tf*128 + wr*64 + i*16 + quad*4;
            float4 bv = *(const float4*)(bias + fr);
            float4 ov = { acc[i][j][0] + bv.x, acc[i][j][1] + bv.y,
                          acc[i][j][2] + bv.z, acc[i][j][3] + bv.w };
            *(float4*)(out + (size_t)tc*DIM + fr) = ov;
        }
    }
}

extern "C" void kernel_launch(void* const* d_in, const int* in_sizes, int n_in,
                              void* d_out, int out_size, void* d_ws, size_t ws_size,
                              hipStream_t stream) {
    (void)in_sizes; (void)n_in; (void)out_size; (void)ws_size;
    const float* x     = (const float*)d_in[0];
    const float* rot   = (const float*)d_in[1];
    const float* trans = (const float*)d_in[2];
    const float* w_qkv = (const float*)d_in[3];
    const float* b_qkv = (const float*)d_in[4];
    const float* w_out = (const float*)d_in[5];
    const float* b_out = (const float*)d_in[6];
    float* out = (float*)d_out;

    const size_t HB = (size_t)BSZ*NH*NSEQ*DH;        // 4,194,304 elements
    ushort* qb   = (ushort*)d_ws;
    ushort* kb   = qb   + HB;
    ushort* vb   = kb   + HB;
    ushort* woTh = vb   + HB;                        // [DIM][INNER]
    ushort* woTl = woTh + (size_t)DIM*INNER;
    ushort* wqTh = woTl + (size_t)DIM*INNER;         // [QKVN][DIM]
    ushort* wqTl = wqTh + (size_t)QKVN*DIM;
    ushort* xh   = wqTl + (size_t)QKVN*DIM;          // [NTOK][DIM]
    ushort* xl   = xh   + HB;
    // omh/oml reuse xh/xl (x consumed by kernel 1; om written by kernel 2)
    ushort* omh  = xh;
    ushort* oml  = xl;

    split_cvt_kernel<<<dim3(NTOK*DIM/1024), 256, 0, stream>>>(x, xh, xl);
    tconv_split_kernel<<<dim3(QKVN/32, DIM/32), 256, 0, stream>>>(w_qkv, wqTh, wqTl, DIM, QKVN);
    tconv_split_kernel<<<dim3(DIM/32, INNER/32), 256, 0, stream>>>(w_out, woTh, woTl, INNER, DIM);

    qkv_gemm_split<<<dim3(NTOK/128, QKVN/128), 256, 0, stream>>>(
        wqTh, wqTl, xh, xl, b_qkv, rot, trans, qb, kb, vb);
    attn_mfma_kernel<<<dim3(NSEQ/64, BSZ*NH), 256, 0, stream>>>(
        qb, kb, vb, rot, trans, omh, oml);
    out_gemm_split<<<dim3(NTOK/128, DIM/128), 256, 0, stream>>>(
        woTh, woTl, omh, oml, b_out, out);
}